// Round 7
// baseline (389.172 us; speedup 1.0000x reference)
//
#include <hip/hip_runtime.h>

#define NB 1024
#define NL 512
#define ND 1000   // ATTN
#define NH 1000   // HID
#define KP 2048   // padded K

typedef __attribute__((ext_vector_type(8))) short bf16x8;
typedef __attribute__((ext_vector_type(4))) float f32x4;

__device__ __forceinline__ unsigned short f2bf(float f) {
    unsigned u = __float_as_uint(f);
    u += 0x7FFFu + ((u >> 16) & 1u);     // RNE
    return (unsigned short)(u >> 16);
}
__device__ __forceinline__ ushort4 f2bf4(float4 v) {
    return make_ushort4(f2bf(v.x), f2bf(v.y), f2bf(v.z), f2bf(v.w));
}

// -------- Kernel 1: prep (absorbed) + fused attn pool --------
// Block b: (a) convert hc row b -> Xb[b][0..999] bf16 (+ zero pad cols
// 2000..2047), convert Wc_w row b -> Wb[b] (zeros for b>=1000); (b) run the
// proven reg-pipelined online-softmax context pass; epilogue writes ctx bf16
// into Xb[b][1000..1999]. proj launches after this kernel (stream order), so
// no cross-block synchronization is needed.
__global__ __launch_bounds__(256, 4) void attn_pool_kernel(
    const float* __restrict__ hc,           // [NB, NH]
    const float* __restrict__ ho,           // [NB, NL, ND]
    const unsigned char* __restrict__ mask, // [NB, NL]
    const float* __restrict__ Wa_w,         // [ND]
    const float* __restrict__ Wa_b,         // [1]
    const float* __restrict__ W,            // [NH, NH+ND]
    unsigned short* __restrict__ Xb,        // [NB, KP] bf16
    unsigned short* __restrict__ Wb)        // [1024, KP] bf16
{
    __shared__ __align__(16) float cacc[4][ND];   // 16000 B combine scratch
    __shared__ unsigned char msk[NL];
    __shared__ float mArr[4], sArr[4];

    const int b    = blockIdx.x;
    const int tid  = threadIdx.x;
    const int wave = tid >> 6;
    const int lane = tid & 63;

    // ---- prep: Xb row b (hc part + pad) ----
    ushort4* xq = (ushort4*)(Xb + (size_t)b * KP);
    if (tid < 250) {
        xq[tid] = f2bf4(((const float4*)(hc + (size_t)b * NH))[tid]);
    } else if (tid < 262) {
        xq[500 + (tid - 250)] = make_ushort4(0, 0, 0, 0);
    }
    // ---- prep: Wb row b ----
    ushort4* wq = (ushort4*)(Wb + (size_t)b * KP);
    if (b < NH) {
        #pragma unroll
        for (int rep = 0; rep < 2; ++rep) {
            int q = tid + rep * 256;
            if (q < 500) {
                wq[q] = f2bf4(((const float4*)(W + (size_t)b * (NH + ND)))[q]);
            } else {
                wq[q] = make_ushort4(0, 0, 0, 0);
            }
        }
    } else {
        wq[tid]       = make_ushort4(0, 0, 0, 0);
        wq[tid + 256] = make_ushort4(0, 0, 0, 0);
    }

    // ---- attn ----
    const unsigned char* mb = mask + (size_t)b * NL;
    msk[tid]       = mb[tid];
    msk[tid + 256] = mb[tid + 256];

    float4 wa[4];
    #pragma unroll
    for (int j = 0; j < 4; ++j) {
        int slot = lane + 64 * j;
        wa[j] = (slot < 250) ? ((const float4*)Wa_w)[slot] : make_float4(0.f, 0.f, 0.f, 0.f);
    }
    const float bias = Wa_b[0];

    const float4* hob = (const float4*)(ho + (size_t)b * NL * ND);

    __syncthreads();  // masks visible

    auto loadRow = [&](int l, float4* v) {
        const float4* rp = hob + (size_t)l * 250;
        #pragma unroll
        for (int j = 0; j < 3; ++j) v[j] = rp[lane + 64 * j];
        v[3] = (lane < 58) ? rp[lane + 192] : make_float4(0.f, 0.f, 0.f, 0.f);
    };

    float  m = -1e30f, s = 0.f;
    float4 acc[4];
    #pragma unroll
    for (int j = 0; j < 4; ++j) acc[j] = make_float4(0.f, 0.f, 0.f, 0.f);

    float4 cur[4], nx1[4], nx2[4];
    loadRow(wave, cur);
    loadRow(4 + wave, nx1);

    #pragma unroll 2
    for (int c = 0; c < 128; ++c) {
        if (c + 2 < 128) loadRow(4 * (c + 2) + wave, nx2);

        float p = 0.f;
        #pragma unroll
        for (int j = 0; j < 4; ++j)
            p += cur[j].x * wa[j].x + cur[j].y * wa[j].y +
                 cur[j].z * wa[j].z + cur[j].w * wa[j].w;
        #pragma unroll
        for (int off = 32; off > 0; off >>= 1) p += __shfl_xor(p, off, 64);

        int l = 4 * c + wave;
        float sc = p + bias;
        if (msk[l]) sc = -10000.f;

        float mn = fmaxf(m, sc);
        if (mn > m) {                       // wave-uniform branch
            float f = __expf(m - mn);
            s *= f;
            #pragma unroll
            for (int j = 0; j < 4; ++j) {
                acc[j].x *= f; acc[j].y *= f; acc[j].z *= f; acc[j].w *= f;
            }
            m = mn;
        }
        float w = __expf(sc - m);
        s += w;
        #pragma unroll
        for (int j = 0; j < 4; ++j) {
            acc[j].x += w * cur[j].x; acc[j].y += w * cur[j].y;
            acc[j].z += w * cur[j].z; acc[j].w += w * cur[j].w;
        }

        #pragma unroll
        for (int j = 0; j < 4; ++j) { cur[j] = nx1[j]; nx1[j] = nx2[j]; }
    }

    // ---- flash-combine the 4 per-wave partials ----
    float4* cw = (float4*)&cacc[wave][0];
    #pragma unroll
    for (int j = 0; j < 4; ++j) {
        int slot = lane + 64 * j;
        if (slot < 250) cw[slot] = acc[j];
    }
    if (lane == 0) { mArr[wave] = m; sArr[wave] = s; }
    __syncthreads();

    float gm = fmaxf(fmaxf(mArr[0], mArr[1]), fmaxf(mArr[2], mArr[3]));
    float f0 = __expf(mArr[0] - gm), f1 = __expf(mArr[1] - gm);
    float f2 = __expf(mArr[2] - gm), f3 = __expf(mArr[3] - gm);
    float S  = f0 * sArr[0] + f1 * sArr[1] + f2 * sArr[2] + f3 * sArr[3];
    float inv = 1.0f / S;

    if (tid < 250) {
        float4 a0 = ((float4*)&cacc[0][0])[tid];
        float4 a1 = ((float4*)&cacc[1][0])[tid];
        float4 a2 = ((float4*)&cacc[2][0])[tid];
        float4 a3 = ((float4*)&cacc[3][0])[tid];
        float4 r;
        r.x = (f0 * a0.x + f1 * a1.x + f2 * a2.x + f3 * a3.x) * inv;
        r.y = (f0 * a0.y + f1 * a1.y + f2 * a2.y + f3 * a3.y) * inv;
        r.z = (f0 * a0.z + f1 * a1.z + f2 * a2.z + f3 * a3.z) * inv;
        r.w = (f0 * a0.w + f1 * a1.w + f2 * a2.w + f3 * a3.w) * inv;
        ((ushort4*)(Xb + (size_t)b * KP + ND))[tid] = f2bf4(r);
    }
}

// -------- Kernel 2: bf16 MFMA projection, 32x64 tiles --------
// grid (32,16) = 512 blocks = 2 blocks/CU = 2 waves/SIMD (latency hiding for
// the L2-resident fragment loads). 4 waves x K=512 each; parallel LDS reduce.
__global__ __launch_bounds__(256, 2) void mfma_proj_kernel(
    const unsigned short* __restrict__ Xb,   // [NB][KP] bf16
    const unsigned short* __restrict__ Wb,   // [1024][KP] bf16
    const float* __restrict__ wb,            // [NH]
    float* __restrict__ out)                 // [NB][NH]
{
    __shared__ float red[4][32][68];   // 34816 B

    const int tid  = threadIdx.x;
    const int wave = tid >> 6;
    const int lane = tid & 63;
    const int row0 = blockIdx.x * 32;
    const int col0 = blockIdx.y * 64;
    const int r    = lane & 15;
    const int g    = lane >> 4;

    const int kbase = wave * 512 + g * 8;
    const unsigned short* xp = Xb + (size_t)(row0 + r) * KP + kbase;
    const unsigned short* wp = Wb + (size_t)(col0 + r) * KP + kbase;

    f32x4 acc[2][4];
    #pragma unroll
    for (int mi = 0; mi < 2; ++mi)
        #pragma unroll
        for (int ni = 0; ni < 4; ++ni)
            acc[mi][ni] = (f32x4){0.f, 0.f, 0.f, 0.f};

    bf16x8 a_[2], b_[4], an[2], bn[4];
    #pragma unroll
    for (int i = 0; i < 2; ++i) a_[i] = *(const bf16x8*)(xp + (size_t)i * 16 * KP);
    #pragma unroll
    for (int i = 0; i < 4; ++i) b_[i] = *(const bf16x8*)(wp + (size_t)i * 16 * KP);

    #pragma unroll 1
    for (int ks = 0; ks < 16; ++ks) {
        if (ks + 1 < 16) {
            const unsigned short* xq = xp + (ks + 1) * 32;
            const unsigned short* wq = wp + (ks + 1) * 32;
            #pragma unroll
            for (int i = 0; i < 2; ++i) an[i] = *(const bf16x8*)(xq + (size_t)i * 16 * KP);
            #pragma unroll
            for (int i = 0; i < 4; ++i) bn[i] = *(const bf16x8*)(wq + (size_t)i * 16 * KP);
        }
        #pragma unroll
        for (int mi = 0; mi < 2; ++mi)
            #pragma unroll
            for (int ni = 0; ni < 4; ++ni)
                acc[mi][ni] = __builtin_amdgcn_mfma_f32_16x16x32_bf16(
                    a_[mi], b_[ni], acc[mi][ni], 0, 0, 0);
        #pragma unroll
        for (int i = 0; i < 2; ++i) a_[i] = an[i];
        #pragma unroll
        for (int i = 0; i < 4; ++i) b_[i] = bn[i];
    }

    // ---- parallel cross-wave reduce ----
    #pragma unroll
    for (int mi = 0; mi < 2; ++mi)
        #pragma unroll
        for (int ni = 0; ni < 4; ++ni)
            #pragma unroll
            for (int j = 0; j < 4; ++j)
                red[wave][mi * 16 + g * 4 + j][ni * 16 + r] = acc[mi][ni][j];
    __syncthreads();

    // ---- sum + bias + store ----
    const int cc = tid & 63;
    const int r0 = (tid >> 6) * 8;
    const int gc = col0 + cc;
    if (gc < NH) {
        float bb = wb[gc];
        #pragma unroll
        for (int i = 0; i < 8; ++i) {
            int rr = r0 + i;
            float v = red[0][rr][cc] + red[1][rr][cc] + red[2][rr][cc] + red[3][rr][cc];
            out[(size_t)(row0 + rr) * NH + gc] = v + bb;
        }
    }
}

extern "C" void kernel_launch(void* const* d_in, const int* in_sizes, int n_in,
                              void* d_out, int out_size, void* d_ws, size_t ws_size,
                              hipStream_t stream) {
    const float* hc           = (const float*)d_in[0];
    const float* ho           = (const float*)d_in[1];
    const unsigned char* mask = (const unsigned char*)d_in[2];
    const float* Wa_w         = (const float*)d_in[3];
    const float* Wa_b         = (const float*)d_in[4];
    const float* Wc_w         = (const float*)d_in[5];
    const float* Wc_b         = (const float*)d_in[6];
    float* out = (float*)d_out;

    unsigned short* Xb = (unsigned short*)d_ws;                       // 4 MB
    unsigned short* Wb = (unsigned short*)d_ws + (size_t)NB * KP;     // 4 MB

    attn_pool_kernel<<<NB, 256, 0, stream>>>(hc, ho, mask, Wa_w, Wa_b, Wc_w, Xb, Wb);
    mfma_proj_kernel<<<dim3(32, 16), 256, 0, stream>>>(Xb, Wb, Wc_b, out);
}